// Round 7
// baseline (126.012 us; speedup 1.0000x reference)
//
#include <hip/hip_runtime.h>

// Paillier sum-pooling = windowed modular product of ciphertexts mod n^2.
// M = NSQ = 46337^2 = 2147117569 < 2^31; inputs int32, output int32 (exact).
//
// Memory-bound: 537 MB read + 134 MB write. R5 structure (best: 116.5 us):
// 4 outputs/thread, per-instruction contiguous int4 loads, grid-stride 2048
// blocks. This round: isolate the nontemporal hint — PLAIN loads (nt was
// never A/B'd separately; suspect nt load path under-performs on the
// 256B-segment read stream), nt stores kept (no re-read, avoid L2 alloc).
//
// Cheap exact mod: 2^31 = M + 366079 -> p mod M folds as
//   p -> (p>>31)*366079 + (p & 0x7FFFFFFF)
// bound chain 2^62.04 -> 2^49.6 -> 2^37.1 -> <= 2170912703 < 2M, closed under
// chaining; single conditional subtract at the end.

#define M   2147117569u
#define K31 366079ull          // 2^31 mod M

typedef int int4v __attribute__((ext_vector_type(4)));

__device__ __forceinline__ unsigned modmul31(unsigned a, unsigned b) {
    unsigned long long p = (unsigned long long)a * b;                                  // < 2^62.04
    p = (unsigned long long)(unsigned)(p >> 31) * K31 + (unsigned)(p & 0x7FFFFFFF);    // < 2^49.6
    p = (unsigned long long)(unsigned)(p >> 31) * K31 + (unsigned)(p & 0x7FFFFFFF);    // < 2^37.1
    p = (unsigned long long)(unsigned)(p >> 31) * K31 + (unsigned)(p & 0x7FFFFFFF);    // <= 2170912703
    return (unsigned)p;
}

__global__ __launch_bounds__(256) void paillier_pool_kernel(
    const int* __restrict__ x, int* __restrict__ out, int nwork)
{
    const int stride = gridDim.x * blockDim.x;               // 524288
    for (int wi = blockIdx.x * blockDim.x + threadIdx.x; wi < nwork; wi += stride) {
        // Each work item produces 4 consecutive-in-c outputs.
        int flat = wi << 2;              // output flat index ((b*128+ho)*128+wo)*64+c
        int c  = flat & 63;
        int wo = (flat >> 6) & 127;
        int ho = (flat >> 13) & 127;
        int b  = flat >> 20;

        // input flat index: ((b*256 + 2*ho)*256 + 2*wo)*64 + c  (< 2^27, fits int)
        int base = ((((b << 8) + (ho << 1)) << 8) + (wo << 1)) * 64 + c;

        int4v v00 = *(const int4v*)(x + base);
        int4v v01 = *(const int4v*)(x + base + 64);
        int4v v10 = *(const int4v*)(x + base + 16384);
        int4v v11 = *(const int4v*)(x + base + 16448);

        int4v r;
#pragma unroll
        for (int k = 0; k < 4; ++k) {
            unsigned t0 = modmul31((unsigned)v00[k], (unsigned)v01[k]);
            unsigned t1 = modmul31((unsigned)v10[k], (unsigned)v11[k]);
            unsigned t  = modmul31(t0, t1);
            if (t >= M) t -= M;
            r[k] = (int)t;
        }

        __builtin_nontemporal_store(r, (int4v*)(out + flat));
    }
}

extern "C" void kernel_launch(void* const* d_in, const int* in_sizes, int n_in,
                              void* d_out, int out_size, void* d_ws, size_t ws_size,
                              hipStream_t stream) {
    const int* x = (const int*)d_in[0];
    int* out = (int*)d_out;

    const int nwork = out_size / 4;      // 33554432 / 4 = 8388608
    const int block = 256;
    const int grid  = 2048;              // 8 blocks/CU, grid-stride x16 iterations

    paillier_pool_kernel<<<grid, block, 0, stream>>>(x, out, nwork);
}

// Round 8
// 116.534 us; speedup vs baseline: 1.0813x; 1.0813x over previous
//
#include <hip/hip_runtime.h>

// Paillier sum-pooling = windowed modular product of ciphertexts mod n^2.
// M = NSQ = 46337^2 = 2147117569 < 2^31; inputs int32, output int32 (exact).
//
// Memory-bound: 537 MB read + 134 MB write (~107 us floor at 6.3 TB/s).
// Best measured config (R5, 116.5 us = 5.76 TB/s = 91.5% of measured copy
// ceiling). Proven by isolation:
//  - grid-stride 2048 blocks (8/CU, 32 waves/CU resident) > one-shot grid
//  - nontemporal loads AND stores (zero reuse; nt skips L2/L3 alloc): plain
//    loads cost +8% (R7), x2 unroll costs +3% (R6), lane-strided layout +28% (R4)
//  - modmul31 folding instead of 64-bit '%' (VALU fully hidden under memory)
//
// Cheap exact mod: 2^31 = M + 366079 -> p mod M folds as
//   p -> (p>>31)*366079 + (p & 0x7FFFFFFF)
// bound chain 2^62.04 -> 2^49.6 -> 2^37.1 -> <= 2170912703 < 2M, closed under
// chaining; single conditional subtract at the end.

#define M   2147117569u
#define K31 366079ull          // 2^31 mod M

typedef int int4v __attribute__((ext_vector_type(4)));

__device__ __forceinline__ unsigned modmul31(unsigned a, unsigned b) {
    unsigned long long p = (unsigned long long)a * b;                                  // < 2^62.04
    p = (unsigned long long)(unsigned)(p >> 31) * K31 + (unsigned)(p & 0x7FFFFFFF);    // < 2^49.6
    p = (unsigned long long)(unsigned)(p >> 31) * K31 + (unsigned)(p & 0x7FFFFFFF);    // < 2^37.1
    p = (unsigned long long)(unsigned)(p >> 31) * K31 + (unsigned)(p & 0x7FFFFFFF);    // <= 2170912703
    return (unsigned)p;
}

__global__ __launch_bounds__(256) void paillier_pool_kernel(
    const int* __restrict__ x, int* __restrict__ out, int nwork)
{
    const int stride = gridDim.x * blockDim.x;               // 524288
    for (int wi = blockIdx.x * blockDim.x + threadIdx.x; wi < nwork; wi += stride) {
        // Each work item produces 4 consecutive-in-c outputs.
        int flat = wi << 2;              // output flat index ((b*128+ho)*128+wo)*64+c
        int c  = flat & 63;
        int wo = (flat >> 6) & 127;
        int ho = (flat >> 13) & 127;
        int b  = flat >> 20;

        // input flat index: ((b*256 + 2*ho)*256 + 2*wo)*64 + c  (< 2^27, fits int)
        int base = ((((b << 8) + (ho << 1)) << 8) + (wo << 1)) * 64 + c;

        int4v v00 = __builtin_nontemporal_load((const int4v*)(x + base));
        int4v v01 = __builtin_nontemporal_load((const int4v*)(x + base + 64));
        int4v v10 = __builtin_nontemporal_load((const int4v*)(x + base + 16384));
        int4v v11 = __builtin_nontemporal_load((const int4v*)(x + base + 16448));

        int4v r;
#pragma unroll
        for (int k = 0; k < 4; ++k) {
            unsigned t0 = modmul31((unsigned)v00[k], (unsigned)v01[k]);
            unsigned t1 = modmul31((unsigned)v10[k], (unsigned)v11[k]);
            unsigned t  = modmul31(t0, t1);
            if (t >= M) t -= M;
            r[k] = (int)t;
        }

        __builtin_nontemporal_store(r, (int4v*)(out + flat));
    }
}

extern "C" void kernel_launch(void* const* d_in, const int* in_sizes, int n_in,
                              void* d_out, int out_size, void* d_ws, size_t ws_size,
                              hipStream_t stream) {
    const int* x = (const int*)d_in[0];
    int* out = (int*)d_out;

    const int nwork = out_size / 4;      // 33554432 / 4 = 8388608
    const int block = 256;
    const int grid  = 2048;              // 8 blocks/CU, grid-stride x16 iterations

    paillier_pool_kernel<<<grid, block, 0, stream>>>(x, out, nwork);
}